// Round 1
// baseline (1610.668 us; speedup 1.0000x reference)
//
#include <hip/hip_runtime.h>

// GCN link-prediction forward.
// Inputs: x[N,256] f32, train_edges[2,E] i32, pos[2,E] i32, neg[2,E] i32,
//         W1[256,256], b1[256], W2[256,128], b2[128]  (all f32)
// Output: logits[2E] f32.

#define NFEAT 256
#define HID   256
#define OUTF  128

// ---------------- degree / dinv ----------------
__global__ void k_init_deg(float* __restrict__ deg, int n) {
    int i = blockIdx.x * blockDim.x + threadIdx.x;
    if (i < n) deg[i] = 1.0f;   // self-loop
}

__global__ void k_count_deg(const int* __restrict__ ei, float* __restrict__ deg, int E) {
    int e = blockIdx.x * blockDim.x + threadIdx.x;
    if (e < E) atomicAdd(&deg[ei[E + e]], 1.0f);   // dst row
}

__global__ void k_rsqrt(float* __restrict__ d, int n) {
    int i = blockIdx.x * blockDim.x + threadIdx.x;
    if (i < n) d[i] = rsqrtf(d[i]);
}

// ---------------- zero fill ----------------
__global__ void k_zero(float4* __restrict__ p, size_t n4) {
    size_t i = (size_t)blockIdx.x * blockDim.x + threadIdx.x;
    if (i < n4) p[i] = make_float4(0.f, 0.f, 0.f, 0.f);
}

// ---------------- GEMM: out[r,c] = dinv[r] * sum_k A[r,k]*W[k,c] ----------------
// Block tile 128x128, thread tile 8x8, BK=32. A row-major [n,K], W row-major [K,M].
#define BK 32
__global__ __launch_bounds__(256) void k_gemm_scaled(
        const float* __restrict__ A, const float* __restrict__ W,
        const float* __restrict__ dinv, float* __restrict__ out,
        int n, int K, int M) {
    __shared__ float As[BK][132];   // [k][row], padded for write-conflict reduction + 16B align
    __shared__ float Bs[BK][128];   // [k][col]

    const int row0 = blockIdx.x * 128;
    const int col0 = blockIdx.y * 128;
    const int t  = threadIdx.x;
    const int cx = t & 15;          // col group: cols cx*8 .. cx*8+7
    const int ry = t >> 4;          // row group: rows ry*8 .. ry*8+7

    float acc[8][8];
#pragma unroll
    for (int i = 0; i < 8; ++i)
#pragma unroll
        for (int j = 0; j < 8; ++j) acc[i][j] = 0.f;

    for (int k0 = 0; k0 < K; k0 += BK) {
#pragma unroll
        for (int it = 0; it < 4; ++it) {
            int qid = t + it * 256;             // 0..1023
            // A tile: 128 rows x 32 k, transposed into As[k][row]
            int r  = qid >> 3;                  // 0..127
            int kq = qid & 7;                   // 0..7 (k quad)
            int grow = row0 + r;
            float4 va = make_float4(0.f, 0.f, 0.f, 0.f);
            if (grow < n)
                va = *(const float4*)&A[(size_t)grow * K + k0 + kq * 4];
            As[kq * 4 + 0][r] = va.x;
            As[kq * 4 + 1][r] = va.y;
            As[kq * 4 + 2][r] = va.z;
            As[kq * 4 + 3][r] = va.w;
            // W tile: 32 k x 128 cols, natural layout
            int kk = qid >> 5;                  // 0..31
            int cq = qid & 31;                  // 0..31
            *(float4*)&Bs[kk][cq * 4] =
                *(const float4*)&W[(size_t)(k0 + kk) * M + col0 + cq * 4];
        }
        __syncthreads();

#pragma unroll
        for (int k = 0; k < BK; ++k) {
            float4 a0 = *(const float4*)&As[k][ry * 8];
            float4 a1 = *(const float4*)&As[k][ry * 8 + 4];
            float4 b0 = *(const float4*)&Bs[k][cx * 8];
            float4 b1 = *(const float4*)&Bs[k][cx * 8 + 4];
            float a[8] = {a0.x, a0.y, a0.z, a0.w, a1.x, a1.y, a1.z, a1.w};
            float b[8] = {b0.x, b0.y, b0.z, b0.w, b1.x, b1.y, b1.z, b1.w};
#pragma unroll
            for (int i = 0; i < 8; ++i)
#pragma unroll
                for (int j = 0; j < 8; ++j) acc[i][j] += a[i] * b[j];
        }
        __syncthreads();
    }

#pragma unroll
    for (int i = 0; i < 8; ++i) {
        int r = row0 + ry * 8 + i;
        if (r >= n) continue;
        float s = dinv[r];
        float4 o0 = make_float4(s * acc[i][0], s * acc[i][1], s * acc[i][2], s * acc[i][3]);
        float4 o1 = make_float4(s * acc[i][4], s * acc[i][5], s * acc[i][6], s * acc[i][7]);
        *(float4*)&out[(size_t)r * M + col0 + cx * 8]     = o0;
        *(float4*)&out[(size_t)r * M + col0 + cx * 8 + 4] = o1;
    }
}

// ---------------- scatter-add: agg[dst] += g[src], one wave per edge ----------------
template <int F>
__global__ void k_scatter(const int* __restrict__ ei, const float* __restrict__ g,
                          float* __restrict__ agg, int E) {
    size_t gid = (size_t)blockIdx.x * blockDim.x + threadIdx.x;
    int e    = (int)(gid >> 6);
    int lane = (int)(gid & 63);
    if (e >= E) return;
    int s = ei[e];
    int d = ei[E + e];
    const float* gs = g + (size_t)s * F;
    float* ad = agg + (size_t)d * F;
#pragma unroll
    for (int j = 0; j < F / 64; ++j) {
        int f = lane + j * 64;
        atomicAdd(&ad[f], gs[f]);
    }
}

// ---------------- epilogue: agg = act(dinv[r]*(agg + g) + b) ----------------
template <int F, bool RELU>
__global__ void k_epilogue(const float* __restrict__ g, float* __restrict__ agg,
                           const float* __restrict__ dinv, const float* __restrict__ bias,
                           int n) {
    size_t i4 = (size_t)blockIdx.x * blockDim.x + threadIdx.x;
    size_t base = i4 * 4;
    if (base >= (size_t)n * F) return;
    int row = (int)(base / F);
    int f   = (int)(base % F);
    float s = dinv[row];
    float4 a = *(const float4*)&agg[base];
    float4 gg = *(const float4*)&g[base];
    float4 b = *(const float4*)&bias[f];
    float4 r;
    r.x = s * (a.x + gg.x) + b.x;
    r.y = s * (a.y + gg.y) + b.y;
    r.z = s * (a.z + gg.z) + b.z;
    r.w = s * (a.w + gg.w) + b.w;
    if (RELU) {
        r.x = fmaxf(r.x, 0.f); r.y = fmaxf(r.y, 0.f);
        r.z = fmaxf(r.z, 0.f); r.w = fmaxf(r.w, 0.f);
    }
    *(float4*)&agg[base] = r;
}

// ---------------- decode: logits[e] = dot(z[a], z[b]) over 128 dims ----------------
__global__ void k_decode(const int* __restrict__ pos, const int* __restrict__ neg,
                         const float* __restrict__ z, float* __restrict__ out, int E) {
    size_t gid = (size_t)blockIdx.x * blockDim.x + threadIdx.x;
    int e    = (int)(gid >> 6);
    int lane = (int)(gid & 63);
    if (e >= 2 * E) return;
    int a, b;
    if (e < E) { a = pos[e];     b = pos[E + e]; }
    else       { a = neg[e - E]; b = neg[e];     }   // neg row1 at E + (e-E) = e
    const float2* za = (const float2*)(z + (size_t)a * OUTF);
    const float2* zb = (const float2*)(z + (size_t)b * OUTF);
    float2 va = za[lane];
    float2 vb = zb[lane];
    float p = va.x * vb.x + va.y * vb.y;
#pragma unroll
    for (int off = 32; off > 0; off >>= 1) p += __shfl_down(p, off);
    if (lane == 0) out[e] = p;
}

extern "C" void kernel_launch(void* const* d_in, const int* in_sizes, int n_in,
                              void* d_out, int out_size, void* d_ws, size_t ws_size,
                              hipStream_t stream) {
    const float* x   = (const float*)d_in[0];
    const int*   tei = (const int*)d_in[1];
    const int*   pos = (const int*)d_in[2];
    const int*   neg = (const int*)d_in[3];
    const float* W1  = (const float*)d_in[4];
    const float* b1  = (const float*)d_in[5];
    const float* W2  = (const float*)d_in[6];
    const float* b2  = (const float*)d_in[7];
    float* out = (float*)d_out;

    const int N = in_sizes[0] / NFEAT;    // 50000
    const int E = in_sizes[1] / 2;        // 800000

    char* ws = (char*)d_ws;
    float* bufA = (float*)ws;                                   // N*256 floats
    float* bufB = (float*)(ws + (size_t)N * HID * 4);           // N*256 floats
    float* dinv = (float*)(ws + 2 * (size_t)N * HID * 4);       // N floats

    float* g1   = bufA;
    float* agg1 = bufB;                        // -> h1 in place
    float* g2   = bufA;                        // reuses g1 (dead after epilogue1)
    float* agg2 = bufA + (size_t)N * OUTF;     // second half of A -> z in place

    // 1) dinv
    k_init_deg<<<(N + 255) / 256, 256, 0, stream>>>(dinv, N);
    k_count_deg<<<(E + 255) / 256, 256, 0, stream>>>(tei, dinv, E);
    k_rsqrt<<<(N + 255) / 256, 256, 0, stream>>>(dinv, N);

    // 2) layer 1
    {
        size_t n4 = (size_t)N * HID / 4;
        k_zero<<<(int)((n4 + 255) / 256), 256, 0, stream>>>((float4*)agg1, n4);
        dim3 grid((N + 127) / 128, HID / 128);
        k_gemm_scaled<<<grid, 256, 0, stream>>>(x, W1, dinv, g1, N, NFEAT, HID);
        size_t nth = (size_t)E * 64;
        k_scatter<HID><<<(int)((nth + 255) / 256), 256, 0, stream>>>(tei, g1, agg1, E);
        size_t ne4 = (size_t)N * HID / 4;
        k_epilogue<HID, true><<<(int)((ne4 + 255) / 256), 256, 0, stream>>>(g1, agg1, dinv, b1, N);
    }

    // 3) layer 2 (h1 = agg1/bufB)
    {
        dim3 grid((N + 127) / 128, OUTF / 128);
        k_gemm_scaled<<<grid, 256, 0, stream>>>(bufB, W2, dinv, g2, N, HID, OUTF);
        size_t n4 = (size_t)N * OUTF / 4;
        k_zero<<<(int)((n4 + 255) / 256), 256, 0, stream>>>((float4*)agg2, n4);
        size_t nth = (size_t)E * 64;
        k_scatter<OUTF><<<(int)((nth + 255) / 256), 256, 0, stream>>>(tei, g2, agg2, E);
        size_t ne4 = (size_t)N * OUTF / 4;
        k_epilogue<OUTF, false><<<(int)((ne4 + 255) / 256), 256, 0, stream>>>(g2, agg2, dinv, b2, N);
    }

    // 4) decode (z = agg2)
    {
        size_t nth = (size_t)2 * E * 64;
        k_decode<<<(int)((nth + 255) / 256), 256, 0, stream>>>(pos, neg, agg2, out, E);
    }
}

// Round 2
// 915.343 us; speedup vs baseline: 1.7596x; 1.7596x over previous
//
#include <hip/hip_runtime.h>

// GCN link-prediction forward, CSR-based aggregation (no feature atomics).
// Inputs: x[N,256] f32, train_edges[2,E] i32, pos[2,E] i32, neg[2,E] i32,
//         W1[256,256], b1[256], W2[256,128], b2[128]  (all f32)
// Output: logits[2E] f32.

#define NFEAT 256
#define HID   256
#define OUTF  128
#define SCAN_T 1024

// ---------------- degree ----------------
__global__ void k_init_deg(float* __restrict__ deg, int n) {
    int i = blockIdx.x * blockDim.x + threadIdx.x;
    if (i < n) deg[i] = 1.0f;   // self-loop
}

__global__ void k_count_deg(const int* __restrict__ ei, float* __restrict__ deg, int E) {
    int e = blockIdx.x * blockDim.x + threadIdx.x;
    if (e < E) atomicAdd(&deg[ei[E + e]], 1.0f);   // dst row
}

// ---------------- scan: rowptr/cursor from deg, dinv in place ----------------
// Single block of 1024 threads; ~49 chunks over N=50000. deg -> dinv in place.
__global__ __launch_bounds__(SCAN_T) void k_scan(
        float* __restrict__ deg_dinv, int* __restrict__ rowptr,
        int* __restrict__ cursor, int n) {
    __shared__ int sdata[SCAN_T];
    __shared__ int s_total;
    int t = threadIdx.x;
    if (t == 0) s_total = 0;
    __syncthreads();
    for (int base = 0; base < n; base += SCAN_T) {
        int i = base + t;
        int v = 0;
        float dg = 1.0f;
        if (i < n) { dg = deg_dinv[i]; v = (int)dg - 1; }  // edge count (no self)
        sdata[t] = v;
        __syncthreads();
        for (int off = 1; off < SCAN_T; off <<= 1) {
            int x = sdata[t];
            int y = (t >= off) ? sdata[t - off] : 0;
            __syncthreads();
            sdata[t] = x + y;
            __syncthreads();
        }
        int excl = sdata[t] - v;   // exclusive scan within chunk
        if (i < n) {
            int rp = s_total + excl;
            rowptr[i] = rp;
            cursor[i] = rp;
            deg_dinv[i] = rsqrtf(dg);
        }
        __syncthreads();
        if (t == 0) s_total += sdata[SCAN_T - 1];
        __syncthreads();
    }
    if (t == 0) rowptr[n] = s_total;
}

// ---------------- fill CSR adjacency (src ids grouped by dst) ----------------
__global__ void k_fill(const int* __restrict__ ei, int* __restrict__ cursor,
                       int* __restrict__ eidx, int E) {
    int e = blockIdx.x * blockDim.x + threadIdx.x;
    if (e < E) {
        int s = ei[e];
        int d = ei[E + e];
        int p = atomicAdd(&cursor[d], 1);
        eidx[p] = s;
    }
}

// ---------------- GEMM: out[r,c] = dinv[r] * sum_k A[r,k]*W[k,c] ----------------
#define BK 32
__global__ __launch_bounds__(256) void k_gemm_scaled(
        const float* __restrict__ A, const float* __restrict__ W,
        const float* __restrict__ dinv, float* __restrict__ out,
        int n, int K, int M) {
    __shared__ float As[BK][132];
    __shared__ float Bs[BK][128];

    const int row0 = blockIdx.x * 128;
    const int col0 = blockIdx.y * 128;
    const int t  = threadIdx.x;
    const int cx = t & 15;
    const int ry = t >> 4;

    float acc[8][8];
#pragma unroll
    for (int i = 0; i < 8; ++i)
#pragma unroll
        for (int j = 0; j < 8; ++j) acc[i][j] = 0.f;

    for (int k0 = 0; k0 < K; k0 += BK) {
#pragma unroll
        for (int it = 0; it < 4; ++it) {
            int qid = t + it * 256;
            int r  = qid >> 3;
            int kq = qid & 7;
            int grow = row0 + r;
            float4 va = make_float4(0.f, 0.f, 0.f, 0.f);
            if (grow < n)
                va = *(const float4*)&A[(size_t)grow * K + k0 + kq * 4];
            As[kq * 4 + 0][r] = va.x;
            As[kq * 4 + 1][r] = va.y;
            As[kq * 4 + 2][r] = va.z;
            As[kq * 4 + 3][r] = va.w;
            int kk = qid >> 5;
            int cq = qid & 31;
            *(float4*)&Bs[kk][cq * 4] =
                *(const float4*)&W[(size_t)(k0 + kk) * M + col0 + cq * 4];
        }
        __syncthreads();

#pragma unroll
        for (int k = 0; k < BK; ++k) {
            float4 a0 = *(const float4*)&As[k][ry * 8];
            float4 a1 = *(const float4*)&As[k][ry * 8 + 4];
            float4 b0 = *(const float4*)&Bs[k][cx * 8];
            float4 b1 = *(const float4*)&Bs[k][cx * 8 + 4];
            float a[8] = {a0.x, a0.y, a0.z, a0.w, a1.x, a1.y, a1.z, a1.w};
            float b[8] = {b0.x, b0.y, b0.z, b0.w, b1.x, b1.y, b1.z, b1.w};
#pragma unroll
            for (int i = 0; i < 8; ++i)
#pragma unroll
                for (int j = 0; j < 8; ++j) acc[i][j] += a[i] * b[j];
        }
        __syncthreads();
    }

#pragma unroll
    for (int i = 0; i < 8; ++i) {
        int r = row0 + ry * 8 + i;
        if (r >= n) continue;
        float s = dinv[r];
        float4 o0 = make_float4(s * acc[i][0], s * acc[i][1], s * acc[i][2], s * acc[i][3]);
        float4 o1 = make_float4(s * acc[i][4], s * acc[i][5], s * acc[i][6], s * acc[i][7]);
        *(float4*)&out[(size_t)r * M + col0 + cx * 8]     = o0;
        *(float4*)&out[(size_t)r * M + col0 + cx * 8 + 4] = o1;
    }
}

// ---------------- CSR gather-aggregate + fused epilogue ----------------
// out[d] = act(dinv[d] * (sum_{s in N(d)} g[s] + g[d]) + b); one wave per node.
template <int F, bool RELU>
__global__ void k_aggregate(const int* __restrict__ rowptr, const int* __restrict__ eidx,
                            const float* __restrict__ g, const float* __restrict__ dinv,
                            const float* __restrict__ bias, float* __restrict__ out, int n) {
    int wid  = (int)(((size_t)blockIdx.x * blockDim.x + threadIdx.x) >> 6);
    int lane = threadIdx.x & 63;
    if (wid >= n) return;
    int j   = rowptr[wid];
    int end = rowptr[wid + 1];
    float sc = dinv[wid];

    if constexpr (F == 256) {
        float4 acc = ((const float4*)(g + (size_t)wid * F))[lane];  // self
        for (; j + 1 < end; j += 2) {
            int s0 = eidx[j];
            int s1 = eidx[j + 1];
            float4 v0 = ((const float4*)(g + (size_t)s0 * F))[lane];
            float4 v1 = ((const float4*)(g + (size_t)s1 * F))[lane];
            acc.x += v0.x + v1.x; acc.y += v0.y + v1.y;
            acc.z += v0.z + v1.z; acc.w += v0.w + v1.w;
        }
        if (j < end) {
            int s0 = eidx[j];
            float4 v0 = ((const float4*)(g + (size_t)s0 * F))[lane];
            acc.x += v0.x; acc.y += v0.y; acc.z += v0.z; acc.w += v0.w;
        }
        float4 b = ((const float4*)bias)[lane];
        float4 r;
        r.x = sc * acc.x + b.x; r.y = sc * acc.y + b.y;
        r.z = sc * acc.z + b.z; r.w = sc * acc.w + b.w;
        if (RELU) {
            r.x = fmaxf(r.x, 0.f); r.y = fmaxf(r.y, 0.f);
            r.z = fmaxf(r.z, 0.f); r.w = fmaxf(r.w, 0.f);
        }
        ((float4*)(out + (size_t)wid * F))[lane] = r;
    } else {  // F == 128
        float2 acc = ((const float2*)(g + (size_t)wid * F))[lane];  // self
        for (; j + 1 < end; j += 2) {
            int s0 = eidx[j];
            int s1 = eidx[j + 1];
            float2 v0 = ((const float2*)(g + (size_t)s0 * F))[lane];
            float2 v1 = ((const float2*)(g + (size_t)s1 * F))[lane];
            acc.x += v0.x + v1.x; acc.y += v0.y + v1.y;
        }
        if (j < end) {
            int s0 = eidx[j];
            float2 v0 = ((const float2*)(g + (size_t)s0 * F))[lane];
            acc.x += v0.x; acc.y += v0.y;
        }
        float2 b = ((const float2*)bias)[lane];
        float2 r;
        r.x = sc * acc.x + b.x; r.y = sc * acc.y + b.y;
        if (RELU) { r.x = fmaxf(r.x, 0.f); r.y = fmaxf(r.y, 0.f); }
        ((float2*)(out + (size_t)wid * F))[lane] = r;
    }
}

// ---------------- decode: logits[e] = dot(z[a], z[b]) over 128 dims ----------------
__global__ void k_decode(const int* __restrict__ pos, const int* __restrict__ neg,
                         const float* __restrict__ z, float* __restrict__ out, int E) {
    size_t gid = (size_t)blockIdx.x * blockDim.x + threadIdx.x;
    int e    = (int)(gid >> 6);
    int lane = (int)(gid & 63);
    if (e >= 2 * E) return;
    int a, b;
    if (e < E) { a = pos[e];     b = pos[E + e]; }
    else       { a = neg[e - E]; b = neg[e];     }
    const float2* za = (const float2*)(z + (size_t)a * OUTF);
    const float2* zb = (const float2*)(z + (size_t)b * OUTF);
    float2 va = za[lane];
    float2 vb = zb[lane];
    float p = va.x * vb.x + va.y * vb.y;
#pragma unroll
    for (int off = 32; off > 0; off >>= 1) p += __shfl_down(p, off);
    if (lane == 0) out[e] = p;
}

extern "C" void kernel_launch(void* const* d_in, const int* in_sizes, int n_in,
                              void* d_out, int out_size, void* d_ws, size_t ws_size,
                              hipStream_t stream) {
    const float* x   = (const float*)d_in[0];
    const int*   tei = (const int*)d_in[1];
    const int*   pos = (const int*)d_in[2];
    const int*   neg = (const int*)d_in[3];
    const float* W1  = (const float*)d_in[4];
    const float* b1  = (const float*)d_in[5];
    const float* W2  = (const float*)d_in[6];
    const float* b2  = (const float*)d_in[7];
    float* out = (float*)d_out;

    const int N = in_sizes[0] / NFEAT;    // 50000
    const int E = in_sizes[1] / 2;        // 800000

    char* ws = (char*)d_ws;
    float* bufA   = (float*)ws;                                    // N*256 f
    float* bufB   = (float*)(ws + (size_t)N * HID * 4);            // N*256 f
    float* dinv   = (float*)(ws + 2 * (size_t)N * HID * 4);        // N f (deg->dinv)
    int*   rowptr = (int*)  (ws + 2 * (size_t)N * HID * 4 + (size_t)N * 4);
    int*   cursor = rowptr + (N + 1);
    int*   eidx   = cursor + N;                                    // E ints

    float* g1 = bufA;
    float* h1 = bufB;
    float* g2 = bufA;                          // reuses g1 (dead after agg1)
    float* z  = bufA + (size_t)N * OUTF;       // second half of bufA

    // 1) degree -> scan -> CSR fill (shared by both layers)
    k_init_deg<<<(N + 255) / 256, 256, 0, stream>>>(dinv, N);
    k_count_deg<<<(E + 255) / 256, 256, 0, stream>>>(tei, dinv, E);
    k_scan<<<1, SCAN_T, 0, stream>>>(dinv, rowptr, cursor, N);
    k_fill<<<(E + 255) / 256, 256, 0, stream>>>(tei, cursor, eidx, E);

    // 2) layer 1: g1 = dinv*(x@W1); h1 = relu(dinv*(agg+self)+b1)
    {
        dim3 grid((N + 127) / 128, HID / 128);
        k_gemm_scaled<<<grid, 256, 0, stream>>>(x, W1, dinv, g1, N, NFEAT, HID);
        size_t nth = (size_t)N * 64;
        k_aggregate<HID, true><<<(int)((nth + 255) / 256), 256, 0, stream>>>(
            rowptr, eidx, g1, dinv, b1, h1, N);
    }

    // 3) layer 2: g2 = dinv*(h1@W2); z = dinv*(agg+self)+b2
    {
        dim3 grid((N + 127) / 128, OUTF / 128);
        k_gemm_scaled<<<grid, 256, 0, stream>>>(h1, W2, dinv, g2, N, HID, OUTF);
        size_t nth = (size_t)N * 64;
        k_aggregate<OUTF, false><<<(int)((nth + 255) / 256), 256, 0, stream>>>(
            rowptr, eidx, g2, dinv, b2, z, N);
    }

    // 4) decode
    {
        size_t nth = (size_t)2 * E * 64;
        k_decode<<<(int)((nth + 255) / 256), 256, 0, stream>>>(pos, neg, z, out, E);
    }
}

// Round 3
// 802.678 us; speedup vs baseline: 2.0066x; 1.1404x over previous
//
#include <hip/hip_runtime.h>

// GCN link-prediction forward, CSR-based aggregation (no feature atomics).
// Inputs: x[N,256] f32, train_edges[2,E] i32, pos[2,E] i32, neg[2,E] i32,
//         W1[256,256], b1[256], W2[256,128], b2[128]  (all f32)
// Output: logits[2E] f32.

#define NFEAT 256
#define HID   256
#define OUTF  128
#define SCAN_T 1024

// ---------------- degree ----------------
__global__ void k_init_deg(float* __restrict__ deg, int n) {
    int i = blockIdx.x * blockDim.x + threadIdx.x;
    if (i < n) deg[i] = 1.0f;   // self-loop
}

__global__ void k_count_deg(const int* __restrict__ ei, float* __restrict__ deg, int E) {
    int e = blockIdx.x * blockDim.x + threadIdx.x;
    if (e < E) atomicAdd(&deg[ei[E + e]], 1.0f);   // dst row
}

// ---------------- scan: rowptr/cursor from deg, dinv in place ----------------
__global__ __launch_bounds__(SCAN_T) void k_scan(
        float* __restrict__ deg_dinv, int* __restrict__ rowptr,
        int* __restrict__ cursor, int n) {
    __shared__ int sdata[SCAN_T];
    __shared__ int s_total;
    int t = threadIdx.x;
    if (t == 0) s_total = 0;
    __syncthreads();
    for (int base = 0; base < n; base += SCAN_T) {
        int i = base + t;
        int v = 0;
        float dg = 1.0f;
        if (i < n) { dg = deg_dinv[i]; v = (int)dg - 1; }  // edge count (no self)
        sdata[t] = v;
        __syncthreads();
        for (int off = 1; off < SCAN_T; off <<= 1) {
            int x = sdata[t];
            int y = (t >= off) ? sdata[t - off] : 0;
            __syncthreads();
            sdata[t] = x + y;
            __syncthreads();
        }
        int excl = sdata[t] - v;   // exclusive scan within chunk
        if (i < n) {
            int rp = s_total + excl;
            rowptr[i] = rp;
            cursor[i] = rp;
            deg_dinv[i] = rsqrtf(dg);
        }
        __syncthreads();
        if (t == 0) s_total += sdata[SCAN_T - 1];
        __syncthreads();
    }
    if (t == 0) rowptr[n] = s_total;
}

// ---------------- fill CSR adjacency (src ids grouped by dst) ----------------
__global__ void k_fill(const int* __restrict__ ei, int* __restrict__ cursor,
                       int* __restrict__ eidx, int E) {
    int e = blockIdx.x * blockDim.x + threadIdx.x;
    if (e < E) {
        int s = ei[e];
        int d = ei[E + e];
        int p = atomicAdd(&cursor[d], 1);
        eidx[p] = s;
    }
}

// ---------------- GEMM: out[r,c] = dinv[r] * sum_k A[r,k]*W[k,c] ----------------
#define BK 32
__global__ __launch_bounds__(256) void k_gemm_scaled(
        const float* __restrict__ A, const float* __restrict__ W,
        const float* __restrict__ dinv, float* __restrict__ out,
        int n, int K, int M) {
    __shared__ float As[BK][132];
    __shared__ float Bs[BK][128];

    const int row0 = blockIdx.x * 128;
    const int col0 = blockIdx.y * 128;
    const int t  = threadIdx.x;
    const int cx = t & 15;
    const int ry = t >> 4;

    float acc[8][8];
#pragma unroll
    for (int i = 0; i < 8; ++i)
#pragma unroll
        for (int j = 0; j < 8; ++j) acc[i][j] = 0.f;

    for (int k0 = 0; k0 < K; k0 += BK) {
#pragma unroll
        for (int it = 0; it < 4; ++it) {
            int qid = t + it * 256;
            int r  = qid >> 3;
            int kq = qid & 7;
            int grow = row0 + r;
            float4 va = make_float4(0.f, 0.f, 0.f, 0.f);
            if (grow < n)
                va = *(const float4*)&A[(size_t)grow * K + k0 + kq * 4];
            As[kq * 4 + 0][r] = va.x;
            As[kq * 4 + 1][r] = va.y;
            As[kq * 4 + 2][r] = va.z;
            As[kq * 4 + 3][r] = va.w;
            int kk = qid >> 5;
            int cq = qid & 31;
            *(float4*)&Bs[kk][cq * 4] =
                *(const float4*)&W[(size_t)(k0 + kk) * M + col0 + cq * 4];
        }
        __syncthreads();

#pragma unroll
        for (int k = 0; k < BK; ++k) {
            float4 a0 = *(const float4*)&As[k][ry * 8];
            float4 a1 = *(const float4*)&As[k][ry * 8 + 4];
            float4 b0 = *(const float4*)&Bs[k][cx * 8];
            float4 b1 = *(const float4*)&Bs[k][cx * 8 + 4];
            float a[8] = {a0.x, a0.y, a0.z, a0.w, a1.x, a1.y, a1.z, a1.w};
            float b[8] = {b0.x, b0.y, b0.z, b0.w, b1.x, b1.y, b1.z, b1.w};
#pragma unroll
            for (int i = 0; i < 8; ++i)
#pragma unroll
                for (int j = 0; j < 8; ++j) acc[i][j] += a[i] * b[j];
        }
        __syncthreads();
    }

#pragma unroll
    for (int i = 0; i < 8; ++i) {
        int r = row0 + ry * 8 + i;
        if (r >= n) continue;
        float s = dinv[r];
        float4 o0 = make_float4(s * acc[i][0], s * acc[i][1], s * acc[i][2], s * acc[i][3]);
        float4 o1 = make_float4(s * acc[i][4], s * acc[i][5], s * acc[i][6], s * acc[i][7]);
        *(float4*)&out[(size_t)r * M + col0 + cx * 8]     = o0;
        *(float4*)&out[(size_t)r * M + col0 + cx * 8 + 4] = o1;
    }
}

// ---------------- CSR gather-aggregate + fused epilogue ----------------
// out[d] = act(dinv[d] * (sum_{s in N(d)} g[s] + g[d]) + b); one wave per node.
template <int F, bool RELU>
__global__ void k_aggregate(const int* __restrict__ rowptr, const int* __restrict__ eidx,
                            const float* __restrict__ g, const float* __restrict__ dinv,
                            const float* __restrict__ bias, float* __restrict__ out, int n) {
    int wid  = (int)(((size_t)blockIdx.x * blockDim.x + threadIdx.x) >> 6);
    int lane = threadIdx.x & 63;
    if (wid >= n) return;
    int j   = rowptr[wid];
    int end = rowptr[wid + 1];
    float sc = dinv[wid];

    if constexpr (F == 256) {
        float4 acc = ((const float4*)(g + (size_t)wid * F))[lane];  // self
        for (; j + 1 < end; j += 2) {
            int s0 = eidx[j];
            int s1 = eidx[j + 1];
            float4 v0 = ((const float4*)(g + (size_t)s0 * F))[lane];
            float4 v1 = ((const float4*)(g + (size_t)s1 * F))[lane];
            acc.x += v0.x + v1.x; acc.y += v0.y + v1.y;
            acc.z += v0.z + v1.z; acc.w += v0.w + v1.w;
        }
        if (j < end) {
            int s0 = eidx[j];
            float4 v0 = ((const float4*)(g + (size_t)s0 * F))[lane];
            acc.x += v0.x; acc.y += v0.y; acc.z += v0.z; acc.w += v0.w;
        }
        float4 b = ((const float4*)bias)[lane];
        float4 r;
        r.x = sc * acc.x + b.x; r.y = sc * acc.y + b.y;
        r.z = sc * acc.z + b.z; r.w = sc * acc.w + b.w;
        if (RELU) {
            r.x = fmaxf(r.x, 0.f); r.y = fmaxf(r.y, 0.f);
            r.z = fmaxf(r.z, 0.f); r.w = fmaxf(r.w, 0.f);
        }
        ((float4*)(out + (size_t)wid * F))[lane] = r;
    } else {  // F == 128
        float2 acc = ((const float2*)(g + (size_t)wid * F))[lane];  // self
        for (; j + 1 < end; j += 2) {
            int s0 = eidx[j];
            int s1 = eidx[j + 1];
            float2 v0 = ((const float2*)(g + (size_t)s0 * F))[lane];
            float2 v1 = ((const float2*)(g + (size_t)s1 * F))[lane];
            acc.x += v0.x + v1.x; acc.y += v0.y + v1.y;
        }
        if (j < end) {
            int s0 = eidx[j];
            float2 v0 = ((const float2*)(g + (size_t)s0 * F))[lane];
            acc.x += v0.x; acc.y += v0.y;
        }
        float2 b = ((const float2*)bias)[lane];
        float2 r;
        r.x = sc * acc.x + b.x; r.y = sc * acc.y + b.y;
        if (RELU) { r.x = fmaxf(r.x, 0.f); r.y = fmaxf(r.y, 0.f); }
        ((float2*)(out + (size_t)wid * F))[lane] = r;
    }
}

// ---------------- decode: logits[e] = dot(z[a], z[b]) over 128 dims ----------------
// 16 lanes per edge (4 edges per wave); each lane: 2x float4 per operand (8 dims).
__global__ void k_decode(const int* __restrict__ pos, const int* __restrict__ neg,
                         const float* __restrict__ z, float* __restrict__ out, int E) {
    size_t gid = (size_t)blockIdx.x * blockDim.x + threadIdx.x;
    int e  = (int)(gid >> 4);           // edge id
    int sl = (int)(threadIdx.x & 15);   // sub-lane within 16-lane group
    if (e >= 2 * E) return;
    int a, b;
    if (e < E) { a = pos[e];     b = pos[E + e]; }
    else       { a = neg[e - E]; b = neg[e];     }   // neg row1 at E + (e-E) = e
    const float4* za = (const float4*)(z + (size_t)a * OUTF);
    const float4* zb = (const float4*)(z + (size_t)b * OUTF);
    float4 a0 = za[sl];
    float4 b0 = zb[sl];
    float4 a1 = za[sl + 16];
    float4 b1 = zb[sl + 16];
    float p = a0.x * b0.x + a0.y * b0.y + a0.z * b0.z + a0.w * b0.w
            + a1.x * b1.x + a1.y * b1.y + a1.z * b1.z + a1.w * b1.w;
    p += __shfl_xor(p, 1);
    p += __shfl_xor(p, 2);
    p += __shfl_xor(p, 4);
    p += __shfl_xor(p, 8);
    if (sl == 0) out[e] = p;
}

extern "C" void kernel_launch(void* const* d_in, const int* in_sizes, int n_in,
                              void* d_out, int out_size, void* d_ws, size_t ws_size,
                              hipStream_t stream) {
    const float* x   = (const float*)d_in[0];
    const int*   tei = (const int*)d_in[1];
    const int*   pos = (const int*)d_in[2];
    const int*   neg = (const int*)d_in[3];
    const float* W1  = (const float*)d_in[4];
    const float* b1  = (const float*)d_in[5];
    const float* W2  = (const float*)d_in[6];
    const float* b2  = (const float*)d_in[7];
    float* out = (float*)d_out;

    const int N = in_sizes[0] / NFEAT;    // 50000
    const int E = in_sizes[1] / 2;        // 800000

    char* ws = (char*)d_ws;
    float* bufA   = (float*)ws;                                    // N*256 f
    float* bufB   = (float*)(ws + (size_t)N * HID * 4);            // N*256 f
    float* dinv   = (float*)(ws + 2 * (size_t)N * HID * 4);        // N f (deg->dinv)
    int*   rowptr = (int*)  (ws + 2 * (size_t)N * HID * 4 + (size_t)N * 4);
    int*   cursor = rowptr + (N + 1);
    int*   eidx   = cursor + N;                                    // E ints

    float* g1 = bufA;
    float* h1 = bufB;
    float* g2 = bufA;                          // reuses g1 (dead after agg1)
    float* z  = bufA + (size_t)N * OUTF;       // second half of bufA

    // 1) degree -> scan -> CSR fill (shared by both layers)
    k_init_deg<<<(N + 255) / 256, 256, 0, stream>>>(dinv, N);
    k_count_deg<<<(E + 255) / 256, 256, 0, stream>>>(tei, dinv, E);
    k_scan<<<1, SCAN_T, 0, stream>>>(dinv, rowptr, cursor, N);
    k_fill<<<(E + 255) / 256, 256, 0, stream>>>(tei, cursor, eidx, E);

    // 2) layer 1: g1 = dinv*(x@W1); h1 = relu(dinv*(agg+self)+b1)
    {
        dim3 grid((N + 127) / 128, HID / 128);
        k_gemm_scaled<<<grid, 256, 0, stream>>>(x, W1, dinv, g1, N, NFEAT, HID);
        size_t nth = (size_t)N * 64;
        k_aggregate<HID, true><<<(int)((nth + 255) / 256), 256, 0, stream>>>(
            rowptr, eidx, g1, dinv, b1, h1, N);
    }

    // 3) layer 2: g2 = dinv*(h1@W2); z = dinv*(agg+self)+b2
    {
        dim3 grid((N + 127) / 128, OUTF / 128);
        k_gemm_scaled<<<grid, 256, 0, stream>>>(h1, W2, dinv, g2, N, HID, OUTF);
        size_t nth = (size_t)N * 64;
        k_aggregate<OUTF, false><<<(int)((nth + 255) / 256), 256, 0, stream>>>(
            rowptr, eidx, g2, dinv, b2, z, N);
    }

    // 4) decode
    {
        size_t nth = (size_t)2 * E * 16;   // 16 lanes per edge
        k_decode<<<(int)((nth + 255) / 256), 256, 0, stream>>>(pos, neg, z, out, E);
    }
}

// Round 4
// 613.898 us; speedup vs baseline: 2.6237x; 1.3075x over previous
//
#include <hip/hip_runtime.h>
#include <hip/hip_fp16.h>

// GCN link-prediction forward. CSR aggregation; fp16 storage for the
// randomly-gathered intermediates (g1, g2, z) to halve cache-miss traffic.
// Inputs: x[N,256] f32, train_edges[2,E] i32, pos[2,E] i32, neg[2,E] i32,
//         W1[256,256], b1[256], W2[256,128], b2[128]  (all f32)
// Output: logits[2E] f32.

#define NFEAT 256
#define HID   256
#define OUTF  128
#define SCAN_T 1024

// ---------------- degree ----------------
__global__ void k_init_deg(float* __restrict__ deg, int n) {
    int i = blockIdx.x * blockDim.x + threadIdx.x;
    if (i < n) deg[i] = 1.0f;   // self-loop
}

__global__ void k_count_deg(const int* __restrict__ ei, float* __restrict__ deg, int E) {
    int e = blockIdx.x * blockDim.x + threadIdx.x;
    if (e < E) atomicAdd(&deg[ei[E + e]], 1.0f);   // dst row
}

// ---------------- scan: rowptr/cursor from deg, dinv in place ----------------
// 1024 threads = 16 waves; wave shuffle scan + 16-entry cross-wave scan.
__global__ __launch_bounds__(SCAN_T) void k_scan(
        float* __restrict__ deg_dinv, int* __restrict__ rowptr,
        int* __restrict__ cursor, int n) {
    __shared__ int swsum[16];
    __shared__ int s_total;
    __shared__ int s_chunk;
    const int t    = threadIdx.x;
    const int wave = t >> 6;
    const int lane = t & 63;
    if (t == 0) s_total = 0;

    for (int base = 0; base < n; base += SCAN_T) {
        int i = base + t;
        float dg = 1.0f;
        int v = 0;
        if (i < n) { dg = deg_dinv[i]; v = (int)dg - 1; }  // edge count (no self)
        // inclusive wave scan
        int sc = v;
#pragma unroll
        for (int off = 1; off < 64; off <<= 1) {
            int y = __shfl_up(sc, off);
            if (lane >= off) sc += y;
        }
        if (lane == 63) swsum[wave] = sc;
        __syncthreads();                       // S1 (also orders s_total init)
        if (t < 16) {
            int w = swsum[t];
            int scw = w;
#pragma unroll
            for (int off = 1; off < 16; off <<= 1) {
                int y = __shfl_up(scw, off);
                if (t >= off) scw += y;
            }
            swsum[t] = scw - w;                // exclusive wave offset
            if (t == 15) s_chunk = scw;        // chunk total
        }
        __syncthreads();                       // S2
        int rp = s_total + swsum[wave] + (sc - v);
        if (i < n) {
            rowptr[i] = rp;
            cursor[i] = rp;
            deg_dinv[i] = rsqrtf(dg);
        }
        __syncthreads();                       // S3 (all s_total/swsum reads done)
        if (t == 0) s_total += s_chunk;
        __syncthreads();                       // S4
    }
    if (t == 0) rowptr[n] = s_total;
}

// ---------------- fill CSR adjacency (src ids grouped by dst) ----------------
__global__ void k_fill(const int* __restrict__ ei, int* __restrict__ cursor,
                       int* __restrict__ eidx, int E) {
    int e = blockIdx.x * blockDim.x + threadIdx.x;
    if (e < E) {
        int s = ei[e];
        int d = ei[E + e];
        int p = atomicAdd(&cursor[d], 1);
        eidx[p] = s;
    }
}

// ---------------- GEMM: out[r,c] = (half) dinv[r] * sum_k A[r,k]*W[k,c] ---------
#define BK 32
__global__ __launch_bounds__(256) void k_gemm_scaled(
        const float* __restrict__ A, const float* __restrict__ W,
        const float* __restrict__ dinv, __half* __restrict__ out,
        int n, int K, int M) {
    __shared__ float As[BK][132];
    __shared__ float Bs[BK][128];

    const int row0 = blockIdx.x * 128;
    const int col0 = blockIdx.y * 128;
    const int t  = threadIdx.x;
    const int cx = t & 15;
    const int ry = t >> 4;

    float acc[8][8];
#pragma unroll
    for (int i = 0; i < 8; ++i)
#pragma unroll
        for (int j = 0; j < 8; ++j) acc[i][j] = 0.f;

    for (int k0 = 0; k0 < K; k0 += BK) {
#pragma unroll
        for (int it = 0; it < 4; ++it) {
            int qid = t + it * 256;
            int r  = qid >> 3;
            int kq = qid & 7;
            int grow = row0 + r;
            float4 va = make_float4(0.f, 0.f, 0.f, 0.f);
            if (grow < n)
                va = *(const float4*)&A[(size_t)grow * K + k0 + kq * 4];
            As[kq * 4 + 0][r] = va.x;
            As[kq * 4 + 1][r] = va.y;
            As[kq * 4 + 2][r] = va.z;
            As[kq * 4 + 3][r] = va.w;
            int kk = qid >> 5;
            int cq = qid & 31;
            *(float4*)&Bs[kk][cq * 4] =
                *(const float4*)&W[(size_t)(k0 + kk) * M + col0 + cq * 4];
        }
        __syncthreads();

#pragma unroll
        for (int k = 0; k < BK; ++k) {
            float4 a0 = *(const float4*)&As[k][ry * 8];
            float4 a1 = *(const float4*)&As[k][ry * 8 + 4];
            float4 b0 = *(const float4*)&Bs[k][cx * 8];
            float4 b1 = *(const float4*)&Bs[k][cx * 8 + 4];
            float a[8] = {a0.x, a0.y, a0.z, a0.w, a1.x, a1.y, a1.z, a1.w};
            float b[8] = {b0.x, b0.y, b0.z, b0.w, b1.x, b1.y, b1.z, b1.w};
#pragma unroll
            for (int i = 0; i < 8; ++i)
#pragma unroll
                for (int j = 0; j < 8; ++j) acc[i][j] += a[i] * b[j];
        }
        __syncthreads();
    }

#pragma unroll
    for (int i = 0; i < 8; ++i) {
        int r = row0 + ry * 8 + i;
        if (r >= n) continue;
        float s = dinv[r];
        union { float4 f; __half2 h[4]; } u;
        u.h[0] = __floats2half2_rn(s * acc[i][0], s * acc[i][1]);
        u.h[1] = __floats2half2_rn(s * acc[i][2], s * acc[i][3]);
        u.h[2] = __floats2half2_rn(s * acc[i][4], s * acc[i][5]);
        u.h[3] = __floats2half2_rn(s * acc[i][6], s * acc[i][7]);
        *(float4*)&out[(size_t)r * M + col0 + cx * 8] = u.f;
    }
}

// ---------------- layer-1 aggregate: fp16 gather -> fp32 out, relu ----------------
// h1[d] = relu(dinv[d]*(sum g1[s] + g1[d]) + b1); one wave/node; lane: 4 features.
__global__ void k_agg1(const int* __restrict__ rowptr, const int* __restrict__ eidx,
                       const __half* __restrict__ g, const float* __restrict__ dinv,
                       const float* __restrict__ bias, float* __restrict__ out, int n) {
    int wid  = (int)(((size_t)blockIdx.x * blockDim.x + threadIdx.x) >> 6);
    int lane = threadIdx.x & 63;
    if (wid >= n) return;
    int j   = rowptr[wid];
    int end = rowptr[wid + 1];
    float sc = dinv[wid];

    union HF2 { float2 f; __half2 h[2]; };
    float4 acc;
    {
        HF2 u; u.f = ((const float2*)(g + (size_t)wid * HID))[lane];  // self
        float2 lo = __half22float2(u.h[0]);
        float2 hi = __half22float2(u.h[1]);
        acc = make_float4(lo.x, lo.y, hi.x, hi.y);
    }
    for (; j + 1 < end; j += 2) {
        int s0 = eidx[j];
        int s1 = eidx[j + 1];
        HF2 u0; u0.f = ((const float2*)(g + (size_t)s0 * HID))[lane];
        HF2 u1; u1.f = ((const float2*)(g + (size_t)s1 * HID))[lane];
        float2 a0 = __half22float2(u0.h[0]), a1 = __half22float2(u0.h[1]);
        float2 c0 = __half22float2(u1.h[0]), c1 = __half22float2(u1.h[1]);
        acc.x += a0.x + c0.x; acc.y += a0.y + c0.y;
        acc.z += a1.x + c1.x; acc.w += a1.y + c1.y;
    }
    if (j < end) {
        int s0 = eidx[j];
        HF2 u0; u0.f = ((const float2*)(g + (size_t)s0 * HID))[lane];
        float2 a0 = __half22float2(u0.h[0]), a1 = __half22float2(u0.h[1]);
        acc.x += a0.x; acc.y += a0.y; acc.z += a1.x; acc.w += a1.y;
    }
    float4 b = ((const float4*)bias)[lane];
    float4 r;
    r.x = fmaxf(sc * acc.x + b.x, 0.f);
    r.y = fmaxf(sc * acc.y + b.y, 0.f);
    r.z = fmaxf(sc * acc.z + b.z, 0.f);
    r.w = fmaxf(sc * acc.w + b.w, 0.f);
    ((float4*)(out + (size_t)wid * HID))[lane] = r;
}

// ---------------- layer-2 aggregate: fp16 gather -> fp16 z ----------------
// z[d] = dinv[d]*(sum g2[s] + g2[d]) + b2; one wave/node; lane: 2 features.
__global__ void k_agg2(const int* __restrict__ rowptr, const int* __restrict__ eidx,
                       const __half* __restrict__ g, const float* __restrict__ dinv,
                       const float* __restrict__ bias, __half* __restrict__ out, int n) {
    int wid  = (int)(((size_t)blockIdx.x * blockDim.x + threadIdx.x) >> 6);
    int lane = threadIdx.x & 63;
    if (wid >= n) return;
    int j   = rowptr[wid];
    int end = rowptr[wid + 1];
    float sc = dinv[wid];

    float2 acc = __half22float2(((const __half2*)(g + (size_t)wid * OUTF))[lane]);  // self
    for (; j + 1 < end; j += 2) {
        int s0 = eidx[j];
        int s1 = eidx[j + 1];
        float2 v0 = __half22float2(((const __half2*)(g + (size_t)s0 * OUTF))[lane]);
        float2 v1 = __half22float2(((const __half2*)(g + (size_t)s1 * OUTF))[lane]);
        acc.x += v0.x + v1.x; acc.y += v0.y + v1.y;
    }
    if (j < end) {
        int s0 = eidx[j];
        float2 v0 = __half22float2(((const __half2*)(g + (size_t)s0 * OUTF))[lane]);
        acc.x += v0.x; acc.y += v0.y;
    }
    float2 b = ((const float2*)bias)[lane];
    __half2 r = __floats2half2_rn(sc * acc.x + b.x, sc * acc.y + b.y);
    ((__half2*)(out + (size_t)wid * OUTF))[lane] = r;
}

// ---------------- decode: logits[e] = dot(z[a], z[b]) over 128 dims (fp16 z) -----
// 16 lanes per edge; each lane one 16-B load (8 halves) per operand.
__global__ void k_decode(const int* __restrict__ pos, const int* __restrict__ neg,
                         const __half* __restrict__ z, float* __restrict__ out, int E) {
    size_t gid = (size_t)blockIdx.x * blockDim.x + threadIdx.x;
    int e  = (int)(gid >> 4);
    int sl = (int)(threadIdx.x & 15);
    if (e >= 2 * E) return;
    int a, b;
    if (e < E) { a = pos[e];     b = pos[E + e]; }
    else       { a = neg[e - E]; b = neg[e];     }   // neg row1 at E + (e-E) = e
    union HF4 { float4 f; __half2 h[4]; };
    HF4 ua, ub;
    ua.f = ((const float4*)(z + (size_t)a * OUTF))[sl];
    ub.f = ((const float4*)(z + (size_t)b * OUTF))[sl];
    float p = 0.f;
#pragma unroll
    for (int k = 0; k < 4; ++k) {
        float2 fa = __half22float2(ua.h[k]);
        float2 fb = __half22float2(ub.h[k]);
        p += fa.x * fb.x + fa.y * fb.y;
    }
    p += __shfl_xor(p, 1);
    p += __shfl_xor(p, 2);
    p += __shfl_xor(p, 4);
    p += __shfl_xor(p, 8);
    if (sl == 0) out[e] = p;
}

extern "C" void kernel_launch(void* const* d_in, const int* in_sizes, int n_in,
                              void* d_out, int out_size, void* d_ws, size_t ws_size,
                              hipStream_t stream) {
    const float* x   = (const float*)d_in[0];
    const int*   tei = (const int*)d_in[1];
    const int*   pos = (const int*)d_in[2];
    const int*   neg = (const int*)d_in[3];
    const float* W1  = (const float*)d_in[4];
    const float* b1  = (const float*)d_in[5];
    const float* W2  = (const float*)d_in[6];
    const float* b2  = (const float*)d_in[7];
    float* out = (float*)d_out;

    const int N = in_sizes[0] / NFEAT;    // 50000
    const int E = in_sizes[1] / 2;        // 800000

    char* ws = (char*)d_ws;
    // region A [0, 51.2MB): g1h (25.6MB) -> then g2h (12.8MB) + zh (12.8MB)
    __half* g1h = (__half*)ws;                                   // N*256 halves
    __half* g2h = (__half*)ws;                                   // N*128 halves (g1 dead)
    __half* zh  = (__half*)(ws + (size_t)N * HID * 2);           // N*128 halves
    // region B [51.2MB, 102.4MB): h1 fp32
    float* h1   = (float*)(ws + (size_t)N * HID * 4);
    float* dinv = (float*)(ws + 2 * (size_t)N * HID * 4);        // N f (deg->dinv)
    int* rowptr = (int*)  (ws + 2 * (size_t)N * HID * 4 + (size_t)N * 4);
    int* cursor = rowptr + (N + 1);
    int* eidx   = cursor + N;                                    // E ints

    // 1) degree -> scan -> CSR fill (shared by both layers)
    k_init_deg<<<(N + 255) / 256, 256, 0, stream>>>(dinv, N);
    k_count_deg<<<(E + 255) / 256, 256, 0, stream>>>(tei, dinv, E);
    k_scan<<<1, SCAN_T, 0, stream>>>(dinv, rowptr, cursor, N);
    k_fill<<<(E + 255) / 256, 256, 0, stream>>>(tei, cursor, eidx, E);

    // 2) layer 1: g1 = (half) dinv*(x@W1); h1 = relu(dinv*(agg+self)+b1)
    {
        dim3 grid((N + 127) / 128, HID / 128);
        k_gemm_scaled<<<grid, 256, 0, stream>>>(x, W1, dinv, g1h, N, NFEAT, HID);
        size_t nth = (size_t)N * 64;
        k_agg1<<<(int)((nth + 255) / 256), 256, 0, stream>>>(
            rowptr, eidx, g1h, dinv, b1, h1, N);
    }

    // 3) layer 2: g2 = (half) dinv*(h1@W2); z = (half) dinv*(agg+self)+b2
    {
        dim3 grid((N + 127) / 128, OUTF / 128);
        k_gemm_scaled<<<grid, 256, 0, stream>>>(h1, W2, dinv, g2h, N, HID, OUTF);
        size_t nth = (size_t)N * 64;
        k_agg2<<<(int)((nth + 255) / 256), 256, 0, stream>>>(
            rowptr, eidx, g2h, dinv, b2, zh, N);
    }

    // 4) decode
    {
        size_t nth = (size_t)2 * E * 16;   // 16 lanes per edge
        k_decode<<<(int)((nth + 255) / 256), 256, 0, stream>>>(pos, neg, zh, out, E);
    }
}

// Round 5
// 495.560 us; speedup vs baseline: 3.2502x; 1.2388x over previous
//
#include <hip/hip_runtime.h>
#include <hip/hip_fp16.h>

// GCN link-prediction forward. CSR aggregation; fp16 storage for all
// gathered intermediates; fp16 MFMA GEMMs (no fp32 MFMA on CDNA4).
// Inputs: x[N,256] f32, train_edges[2,E] i32, pos[2,E] i32, neg[2,E] i32,
//         W1[256,256], b1[256], W2[256,128], b2[128]  (all f32)
// Output: logits[2E] f32.

#define NFEAT 256
#define HID   256
#define OUTF  128
#define SCAN_T 1024

typedef _Float16 f16x8 __attribute__((ext_vector_type(8)));
typedef float    f32x4 __attribute__((ext_vector_type(4)));

// ---------------- degree ----------------
__global__ void k_init_deg(float* __restrict__ deg, int n) {
    int i = blockIdx.x * blockDim.x + threadIdx.x;
    if (i < n) deg[i] = 1.0f;   // self-loop
}

__global__ void k_count_deg(const int* __restrict__ ei, float* __restrict__ deg, int E) {
    int e = blockIdx.x * blockDim.x + threadIdx.x;
    if (e < E) atomicAdd(&deg[ei[E + e]], 1.0f);   // dst row
}

// ---------------- scan: rowptr/cursor from deg, dinv in place ----------------
__global__ __launch_bounds__(SCAN_T) void k_scan(
        float* __restrict__ deg_dinv, int* __restrict__ rowptr,
        int* __restrict__ cursor, int n) {
    __shared__ int swsum[16];
    __shared__ int s_total;
    __shared__ int s_chunk;
    const int t    = threadIdx.x;
    const int wave = t >> 6;
    const int lane = t & 63;
    if (t == 0) s_total = 0;

    for (int base = 0; base < n; base += SCAN_T) {
        int i = base + t;
        float dg = 1.0f;
        int v = 0;
        if (i < n) { dg = deg_dinv[i]; v = (int)dg - 1; }  // edge count (no self)
        int sc = v;
#pragma unroll
        for (int off = 1; off < 64; off <<= 1) {
            int y = __shfl_up(sc, off);
            if (lane >= off) sc += y;
        }
        if (lane == 63) swsum[wave] = sc;
        __syncthreads();
        if (t < 16) {
            int w = swsum[t];
            int scw = w;
#pragma unroll
            for (int off = 1; off < 16; off <<= 1) {
                int y = __shfl_up(scw, off);
                if (t >= off) scw += y;
            }
            swsum[t] = scw - w;
            if (t == 15) s_chunk = scw;
        }
        __syncthreads();
        int rp = s_total + swsum[wave] + (sc - v);
        if (i < n) {
            rowptr[i] = rp;
            cursor[i] = rp;
            deg_dinv[i] = rsqrtf(dg);
        }
        __syncthreads();
        if (t == 0) s_total += s_chunk;
        __syncthreads();
    }
    if (t == 0) rowptr[n] = s_total;
}

// ---------------- fill CSR adjacency (src ids grouped by dst) ----------------
__global__ void k_fill(const int* __restrict__ ei, int* __restrict__ cursor,
                       int* __restrict__ eidx, int E) {
    int e = blockIdx.x * blockDim.x + threadIdx.x;
    if (e < E) {
        int s = ei[e];
        int d = ei[E + e];
        int p = atomicAdd(&cursor[d], 1);
        eidx[p] = s;
    }
}

// ---------------- W transpose+convert: Wt[m][k] = (half)W[k][m] ----------------
__global__ __launch_bounds__(256) void k_wt(const float* __restrict__ W,
                                            __half* __restrict__ Wt, int K, int M) {
    __shared__ float tile[32][33];
    int k0 = blockIdx.x * 32, m0 = blockIdx.y * 32;
    int tx = threadIdx.x & 31, ty = threadIdx.x >> 5;  // ty 0..7
#pragma unroll
    for (int r = 0; r < 4; ++r)
        tile[ty + r * 8][tx] = W[(size_t)(k0 + ty + r * 8) * M + m0 + tx];
    __syncthreads();
#pragma unroll
    for (int r = 0; r < 4; ++r)
        Wt[(size_t)(m0 + ty + r * 8) * K + k0 + tx] = __float2half(tile[tx][ty + r * 8]);
}

// ---------------- MFMA GEMM: out = (half)(dinv[r] * A @ Wt^T) ----------------
// Block: 256 threads = 4 waves (2x2). Block tile (2*MT*16) x 128, wave (MT*16) x 64.
// A: [n][K] (f32 if AF32 else f16). Wt: [M][K] f16. K % 32 == 0.
template <int MT, bool AF32>
__global__ __launch_bounds__(256) void k_gemm_mfma(
        const void* __restrict__ Aptr, const __half* __restrict__ Wt,
        const float* __restrict__ dinv, __half* __restrict__ outp,
        int n, int K, int M) {
    constexpr int BM = 2 * MT * 16;
    __shared__ __half As[BM][40];      // [row][k], +8 pad: 2-way banks (free)
    __shared__ __half Bs[128][40];     // [col][k]
    __shared__ __half Cs[4][16][72];   // per-wave C repack (16B-aligned rows)

    const int t    = threadIdx.x;
    const int wave = t >> 6;
    const int lane = t & 63;
    const int row0 = blockIdx.x * BM;
    const int col0 = blockIdx.y * 128;
    const int wm = wave >> 1, wn = wave & 1;
    const int lr = lane & 15;          // fragment m/n index
    const int kq = lane >> 4;          // k-quad: k = kq*8 + j

    f32x4 acc[MT][4];
#pragma unroll
    for (int i = 0; i < MT; ++i)
#pragma unroll
        for (int j = 0; j < 4; ++j) acc[i][j] = (f32x4){0.f, 0.f, 0.f, 0.f};

    for (int k0 = 0; k0 < K; k0 += 32) {
        // ---- stage A tile: BM rows x 32 k ----
        if (AF32) {
            const float* A = (const float*)Aptr;
#pragma unroll
            for (int it = 0; it < BM * 8 / 256; ++it) {
                int q = t + it * 256;
                int r = q >> 3, c4 = q & 7;       // c4: which 4-float chunk
                int gr = min(row0 + r, n - 1);
                float4 v = *(const float4*)&A[(size_t)gr * K + k0 + c4 * 4];
                __half2* dst = (__half2*)&As[r][c4 * 4];
                dst[0] = __floats2half2_rn(v.x, v.y);
                dst[1] = __floats2half2_rn(v.z, v.w);
            }
        } else {
            const __half* A = (const __half*)Aptr;
#pragma unroll
            for (int it = 0; it < BM * 4 / 256; ++it) {
                int q = t + it * 256;
                int r = q >> 2, c8 = q & 3;       // c8: which 8-half chunk
                int gr = min(row0 + r, n - 1);
                *(float4*)&As[r][c8 * 8] = *(const float4*)&A[(size_t)gr * K + k0 + c8 * 8];
            }
        }
        // ---- stage B tile: 128 cols x 32 k from Wt ----
#pragma unroll
        for (int it = 0; it < 2; ++it) {
            int q = t + it * 256;
            int r = q >> 2, c8 = q & 3;
            *(float4*)&Bs[r][c8 * 8] = *(const float4*)&Wt[(size_t)(col0 + r) * K + k0 + c8 * 8];
        }
        __syncthreads();

        f16x8 b[4];
#pragma unroll
        for (int j = 0; j < 4; ++j)
            b[j] = *(const f16x8*)&Bs[wn * 64 + j * 16 + lr][kq * 8];
#pragma unroll
        for (int i = 0; i < MT; ++i) {
            f16x8 a = *(const f16x8*)&As[wm * MT * 16 + i * 16 + lr][kq * 8];
#pragma unroll
            for (int j = 0; j < 4; ++j)
                acc[i][j] = __builtin_amdgcn_mfma_f32_16x16x32_f16(a, b[j], acc[i][j], 0, 0, 0);
        }
        __syncthreads();
    }

    // ---- epilogue: scale by dinv, f16 convert, repack via LDS, 16-B stores ----
#pragma unroll
    for (int i = 0; i < MT; ++i) {
        int gr0 = row0 + wm * MT * 16 + i * 16;
        float dv[4];
#pragma unroll
        for (int r = 0; r < 4; ++r)
            dv[r] = dinv[min(gr0 + kq * 4 + r, n - 1)];
        __syncthreads();   // protect Cs reuse across i iterations
#pragma unroll
        for (int j = 0; j < 4; ++j)
#pragma unroll
            for (int r = 0; r < 4; ++r)
                Cs[wave][kq * 4 + r][j * 16 + lr] = __float2half(acc[i][j][r] * dv[r]);
        __syncthreads();
        int r1 = lane >> 3, c1 = (lane & 7) * 8;
#pragma unroll
        for (int h = 0; h < 2; ++h) {
            int grow = gr0 + r1 + h * 8;
            if (grow < n)
                *(float4*)&outp[(size_t)grow * M + col0 + wn * 64 + c1] =
                    *(const float4*)&Cs[wave][r1 + h * 8][c1];
        }
    }
}

// ---------------- layer-1 aggregate: fp16 gather -> fp16 h1, relu ----------------
__global__ void k_agg1(const int* __restrict__ rowptr, const int* __restrict__ eidx,
                       const __half* __restrict__ g, const float* __restrict__ dinv,
                       const float* __restrict__ bias, __half* __restrict__ out, int n) {
    int wid  = (int)(((size_t)blockIdx.x * blockDim.x + threadIdx.x) >> 6);
    int lane = threadIdx.x & 63;
    if (wid >= n) return;
    int j   = rowptr[wid];
    int end = rowptr[wid + 1];
    float sc = dinv[wid];

    union HF2 { float2 f; __half2 h[2]; };
    float4 acc;
    {
        HF2 u; u.f = ((const float2*)(g + (size_t)wid * HID))[lane];  // self
        float2 lo = __half22float2(u.h[0]);
        float2 hi = __half22float2(u.h[1]);
        acc = make_float4(lo.x, lo.y, hi.x, hi.y);
    }
    for (; j + 1 < end; j += 2) {
        int s0 = eidx[j];
        int s1 = eidx[j + 1];
        HF2 u0; u0.f = ((const float2*)(g + (size_t)s0 * HID))[lane];
        HF2 u1; u1.f = ((const float2*)(g + (size_t)s1 * HID))[lane];
        float2 a0 = __half22float2(u0.h[0]), a1 = __half22float2(u0.h[1]);
        float2 c0 = __half22float2(u1.h[0]), c1 = __half22float2(u1.h[1]);
        acc.x += a0.x + c0.x; acc.y += a0.y + c0.y;
        acc.z += a1.x + c1.x; acc.w += a1.y + c1.y;
    }
    if (j < end) {
        int s0 = eidx[j];
        HF2 u0; u0.f = ((const float2*)(g + (size_t)s0 * HID))[lane];
        float2 a0 = __half22float2(u0.h[0]), a1 = __half22float2(u0.h[1]);
        acc.x += a0.x; acc.y += a0.y; acc.z += a1.x; acc.w += a1.y;
    }
    float4 b = ((const float4*)bias)[lane];
    HF2 r;
    r.h[0] = __floats2half2_rn(fmaxf(sc * acc.x + b.x, 0.f), fmaxf(sc * acc.y + b.y, 0.f));
    r.h[1] = __floats2half2_rn(fmaxf(sc * acc.z + b.z, 0.f), fmaxf(sc * acc.w + b.w, 0.f));
    ((float2*)(out + (size_t)wid * HID))[lane] = r.f;
}

// ---------------- layer-2 aggregate: fp16 gather -> fp16 z ----------------
__global__ void k_agg2(const int* __restrict__ rowptr, const int* __restrict__ eidx,
                       const __half* __restrict__ g, const float* __restrict__ dinv,
                       const float* __restrict__ bias, __half* __restrict__ out, int n) {
    int wid  = (int)(((size_t)blockIdx.x * blockDim.x + threadIdx.x) >> 6);
    int lane = threadIdx.x & 63;
    if (wid >= n) return;
    int j   = rowptr[wid];
    int end = rowptr[wid + 1];
    float sc = dinv[wid];

    float2 acc = __half22float2(((const __half2*)(g + (size_t)wid * OUTF))[lane]);  // self
    for (; j + 1 < end; j += 2) {
        int s0 = eidx[j];
        int s1 = eidx[j + 1];
        float2 v0 = __half22float2(((const __half2*)(g + (size_t)s0 * OUTF))[lane]);
        float2 v1 = __half22float2(((const __half2*)(g + (size_t)s1 * OUTF))[lane]);
        acc.x += v0.x + v1.x; acc.y += v0.y + v1.y;
    }
    if (j < end) {
        int s0 = eidx[j];
        float2 v0 = __half22float2(((const __half2*)(g + (size_t)s0 * OUTF))[lane]);
        acc.x += v0.x; acc.y += v0.y;
    }
    float2 b = ((const float2*)bias)[lane];
    __half2 r = __floats2half2_rn(sc * acc.x + b.x, sc * acc.y + b.y);
    ((__half2*)(out + (size_t)wid * OUTF))[lane] = r;
}

// ---------------- decode: logits[e] = dot(z[a], z[b]) over 128 dims (fp16 z) -----
__global__ void k_decode(const int* __restrict__ pos, const int* __restrict__ neg,
                         const __half* __restrict__ z, float* __restrict__ out, int E) {
    size_t gid = (size_t)blockIdx.x * blockDim.x + threadIdx.x;
    int e  = (int)(gid >> 4);
    int sl = (int)(threadIdx.x & 15);
    if (e >= 2 * E) return;
    int a, b;
    if (e < E) { a = pos[e];     b = pos[E + e]; }
    else       { a = neg[e - E]; b = neg[e];     }
    union HF4 { float4 f; __half2 h[4]; };
    HF4 ua, ub;
    ua.f = ((const float4*)(z + (size_t)a * OUTF))[sl];
    ub.f = ((const float4*)(z + (size_t)b * OUTF))[sl];
    float p = 0.f;
#pragma unroll
    for (int k = 0; k < 4; ++k) {
        float2 fa = __half22float2(ua.h[k]);
        float2 fb = __half22float2(ub.h[k]);
        p += fa.x * fb.x + fa.y * fb.y;
    }
    p += __shfl_xor(p, 1);
    p += __shfl_xor(p, 2);
    p += __shfl_xor(p, 4);
    p += __shfl_xor(p, 8);
    if (sl == 0) out[e] = p;
}

extern "C" void kernel_launch(void* const* d_in, const int* in_sizes, int n_in,
                              void* d_out, int out_size, void* d_ws, size_t ws_size,
                              hipStream_t stream) {
    const float* x   = (const float*)d_in[0];
    const int*   tei = (const int*)d_in[1];
    const int*   pos = (const int*)d_in[2];
    const int*   neg = (const int*)d_in[3];
    const float* W1  = (const float*)d_in[4];
    const float* b1  = (const float*)d_in[5];
    const float* W2  = (const float*)d_in[6];
    const float* b2  = (const float*)d_in[7];
    float* out = (float*)d_out;

    const int N = in_sizes[0] / NFEAT;    // 50000
    const int E = in_sizes[1] / 2;        // 800000

    char* ws = (char*)d_ws;
    size_t off = 0;
    __half* g1h = (__half*)(ws + off);                 // N*256 halves
    __half* g2h = (__half*)(ws + off);                 // N*128 halves (g1 dead)
    __half* zh  = (__half*)(ws + off + (size_t)N * OUTF * 2);
    off += (size_t)N * HID * 2;
    __half* h1h = (__half*)(ws + off);  off += (size_t)N * HID * 2;
    float*  dinv = (float*)(ws + off);  off += (size_t)N * 4;
    int* rowptr = (int*)(ws + off);     off += (size_t)(N + 1) * 4;
    int* cursor = (int*)(ws + off);     off += (size_t)N * 4;
    int* eidx   = (int*)(ws + off);     off += (size_t)E * 4;
    __half* W1t = (__half*)(ws + off);  off += (size_t)NFEAT * HID * 2;
    __half* W2t = (__half*)(ws + off);  off += (size_t)HID * OUTF * 2;

    // 0) weight transpose+convert
    { dim3 g(NFEAT / 32, HID / 32);  k_wt<<<g, 256, 0, stream>>>(W1, W1t, NFEAT, HID); }
    { dim3 g(HID / 32, OUTF / 32);   k_wt<<<g, 256, 0, stream>>>(W2, W2t, HID, OUTF); }

    // 1) degree -> scan -> CSR fill (shared by both layers)
    k_init_deg<<<(N + 255) / 256, 256, 0, stream>>>(dinv, N);
    k_count_deg<<<(E + 255) / 256, 256, 0, stream>>>(tei, dinv, E);
    k_scan<<<1, SCAN_T, 0, stream>>>(dinv, rowptr, cursor, N);
    k_fill<<<(E + 255) / 256, 256, 0, stream>>>(tei, cursor, eidx, E);

    // 2) layer 1: g1 = (half) dinv*(x@W1); h1 = (half) relu(dinv*(agg+self)+b1)
    {
        dim3 grid((N + 127) / 128, HID / 128);
        k_gemm_mfma<4, true><<<grid, 256, 0, stream>>>(x, W1t, dinv, g1h, N, NFEAT, HID);
        size_t nth = (size_t)N * 64;
        k_agg1<<<(int)((nth + 255) / 256), 256, 0, stream>>>(
            rowptr, eidx, g1h, dinv, b1, h1h, N);
    }

    // 3) layer 2: g2 = (half) dinv*(h1@W2); z = (half) dinv*(agg+self)+b2
    {
        dim3 grid((N + 63) / 64, OUTF / 128);
        k_gemm_mfma<2, false><<<grid, 256, 0, stream>>>(h1h, W2t, dinv, g2h, N, HID, OUTF);
        size_t nth = (size_t)N * 64;
        k_agg2<<<(int)((nth + 255) / 256), 256, 0, stream>>>(
            rowptr, eidx, g2h, dinv, b2, zh, N);
    }

    // 4) decode
    {
        size_t nth = (size_t)2 * E * 16;   // 16 lanes per edge
        k_decode<<<(int)((nth + 255) / 256), 256, 0, stream>>>(pos, neg, zh, out, E);
    }
}